// Round 1
// baseline (915.783 us; speedup 1.0000x reference)
//
#include <hip/hip_runtime.h>
#include <hip/hip_bf16.h>
#include <math.h>

#define T_TOK 16384
#define DMODEL 1024
#define HID 512
#define NEXP 16

typedef __bf16 bf16_8 __attribute__((ext_vector_type(8)));
typedef float f32_4 __attribute__((ext_vector_type(4)));

__device__ inline bf16_8 zero_bf16_8() {
  bf16_8 v;
#pragma unroll
  for (int i = 0; i < 8; ++i) v[i] = (__bf16)0.f;
  return v;
}

// ---------------- gating: logits, softmax, top-2, token lists; also x -> bf16 ----------------
__global__ __launch_bounds__(256) void gate_kernel(
    const float* __restrict__ x, const float* __restrict__ gw, const float* __restrict__ gb,
    __bf16* __restrict__ xb, int* __restrict__ counts,
    int* __restrict__ tok_list, float* __restrict__ tok_w)
{
  int wave = threadIdx.x >> 6;
  int lane = threadIdx.x & 63;
  int t = blockIdx.x * 4 + wave;
  const float* xr = x + (size_t)t * DMODEL;
  float acc[NEXP];
#pragma unroll
  for (int e = 0; e < NEXP; ++e) acc[e] = 0.f;
  for (int i = lane; i < DMODEL; i += 64) {
    float xv = xr[i];
    xb[(size_t)t * DMODEL + i] = (__bf16)xv;
    const float* g = gw + (size_t)i * NEXP;
#pragma unroll
    for (int e = 0; e < NEXP; ++e) acc[e] = fmaf(xv, g[e], acc[e]);
  }
#pragma unroll
  for (int e = 0; e < NEXP; ++e) {
    float v = acc[e];
#pragma unroll
    for (int s = 32; s > 0; s >>= 1) v += __shfl_xor(v, s, 64);
    acc[e] = v;
  }
  if (lane == 0) {
    float mx = -1e30f;
#pragma unroll
    for (int e = 0; e < NEXP; ++e) { acc[e] += gb[e]; mx = fmaxf(mx, acc[e]); }
    float Z = 0.f;
#pragma unroll
    for (int e = 0; e < NEXP; ++e) { acc[e] = expf(acc[e] - mx); Z += acc[e]; }
    // top-2 on scores (softmax is monotonic in logits); ties -> lowest index, like lax.top_k
    int i0 = 0; float s0 = acc[0];
#pragma unroll
    for (int e = 1; e < NEXP; ++e) if (acc[e] > s0) { s0 = acc[e]; i0 = e; }
    int i1 = -1; float s1 = -1e30f;
#pragma unroll
    for (int e = 0; e < NEXP; ++e) if (e != i0 && acc[e] > s1) { s1 = acc[e]; i1 = e; }
    s0 /= Z; s1 /= Z;
    float dn = s0 + s1 + 1e-9f;
    float w0 = s0 / dn, w1 = s1 / dn;
    int p0 = atomicAdd(&counts[i0], 1);
    tok_list[i0 * T_TOK + p0] = t; tok_w[i0 * T_TOK + p0] = w0;
    int p1 = atomicAdd(&counts[i1], 1);
    tok_list[i1 * T_TOK + p1] = t; tok_w[i1 * T_TOK + p1] = w1;
  }
}

// ---------------- prefix-sum of counts + aux loss ----------------
__global__ void scan_kernel(const int* __restrict__ counts, int* __restrict__ offsets,
                            float* __restrict__ aux_out)
{
  if (threadIdx.x == 0) {
    int off = 0; float pen = 0.f;
    const float cap = 1.25f * (float)(T_TOK * 2) / (float)NEXP; // 2560
    for (int e = 0; e < NEXP; ++e) {
      offsets[e] = off;
      off += counts[e];
      float ld = (float)counts[e] - cap;
      pen += ld > 0.f ? ld : 0.f;
    }
    offsets[NEXP] = off;
    aux_out[0] = 0.01f * pen / (float)NEXP / (float)T_TOK;
  }
}

// ---------------- tiled transpose fp32[E][R][C] -> bf16[E][C][R] ----------------
template<int R, int C>
__global__ __launch_bounds__(256) void transpose_bf16_kernel(const float* __restrict__ in,
                                                             __bf16* __restrict__ out)
{
  __shared__ float tile[32][33];
  int e = blockIdx.z;
  int c0 = blockIdx.x * 32, r0 = blockIdx.y * 32;
  const float* src = in + ((size_t)e * R + r0) * C + c0;
#pragma unroll
  for (int i = 0; i < 4; ++i) {
    int r = threadIdx.y + i * 8;
    tile[r][threadIdx.x] = src[(size_t)r * C + threadIdx.x];
  }
  __syncthreads();
  __bf16* dst = out + ((size_t)e * C + c0) * R + r0;
#pragma unroll
  for (int i = 0; i < 4; ++i) {
    int c = threadIdx.y + i * 8;
    dst[(size_t)c * R + threadIdx.x] = (__bf16)tile[threadIdx.x][c];
  }
}

// ---------------- grouped GEMM tiles ----------------
#define BM 128
#define BN 64
#define BK 32
#define LDSS 40  // bf16 elements per LDS row (pad: 80B stride -> <=2-way bank alias, free)

// FFN1: h = (x@gp + b) * silu(x@up + b), per (expert, token-slot). A gathered via tok_list.
__global__ __launch_bounds__(256) void ffn1_kernel(
    const __bf16* __restrict__ xb, const __bf16* __restrict__ gpb, const __bf16* __restrict__ upb,
    const float* __restrict__ gp_b, const float* __restrict__ up_b,
    const int* __restrict__ counts, const int* __restrict__ offsets,
    const int* __restrict__ tok_list, __bf16* __restrict__ h)
{
  int e = blockIdx.z;
  int cnt = counts[e];
  int m0 = blockIdx.y * BM;
  if (m0 >= cnt) return;
  int n0 = blockIdx.x * BN;

  __shared__ __align__(16) __bf16 As[BM * LDSS];
  __shared__ __align__(16) __bf16 Bgs[BN * LDSS];
  __shared__ __align__(16) __bf16 Bus[BN * LDSS];
  __shared__ int toks[BM];

  int tid = threadIdx.x;
  if (tid < BM) {
    int r = m0 + tid;
    toks[tid] = (r < cnt) ? tok_list[e * T_TOK + r] : -1;
  }

  int wave = tid >> 6, lane = tid & 63;
  int quad = lane >> 4, l16 = lane & 15;

  f32_4 accg[2][4], accu[2][4];
  {
    f32_4 z = {0.f, 0.f, 0.f, 0.f};
#pragma unroll
    for (int a = 0; a < 2; ++a)
#pragma unroll
      for (int b = 0; b < 4; ++b) { accg[a][b] = z; accu[a][b] = z; }
  }

  const __bf16* Bg = gpb + ((size_t)e * HID + n0) * DMODEL;
  const __bf16* Bu = upb + ((size_t)e * HID + n0) * DMODEL;
  __syncthreads();

  for (int k0 = 0; k0 < DMODEL; k0 += BK) {
    // stage A: 128 rows x 32 k (16B chunks), rows gathered by token id
#pragma unroll
    for (int c = 0; c < 2; ++c) {
      int idx = tid + c * 256;
      int r = idx >> 2, ko = (idx & 3) * 8;
      int t = toks[r];
      bf16_8 v = (t >= 0) ? *(const bf16_8*)(xb + (size_t)t * DMODEL + k0 + ko) : zero_bf16_8();
      *(bf16_8*)(As + r * LDSS + ko) = v;
    }
    // stage B^T tiles (N-major weights): 64 rows x 32 k each
    {
      int r = tid >> 2, ko = (tid & 3) * 8;
      *(bf16_8*)(Bgs + r * LDSS + ko) = *(const bf16_8*)(Bg + (size_t)r * DMODEL + k0 + ko);
      *(bf16_8*)(Bus + r * LDSS + ko) = *(const bf16_8*)(Bu + (size_t)r * DMODEL + k0 + ko);
    }
    __syncthreads();

    bf16_8 af[2];
#pragma unroll
    for (int mb = 0; mb < 2; ++mb)
      af[mb] = *(const bf16_8*)(As + (wave * 32 + mb * 16 + l16) * LDSS + quad * 8);
#pragma unroll
    for (int nb = 0; nb < 4; ++nb) {
      bf16_8 bg = *(const bf16_8*)(Bgs + (nb * 16 + l16) * LDSS + quad * 8);
      bf16_8 bu = *(const bf16_8*)(Bus + (nb * 16 + l16) * LDSS + quad * 8);
#pragma unroll
      for (int mb = 0; mb < 2; ++mb) {
        accg[mb][nb] = __builtin_amdgcn_mfma_f32_16x16x32_bf16(af[mb], bg, accg[mb][nb], 0, 0, 0);
        accu[mb][nb] = __builtin_amdgcn_mfma_f32_16x16x32_bf16(af[mb], bu, accu[mb][nb], 0, 0, 0);
      }
    }
    __syncthreads();
  }

  int offe = offsets[e];
#pragma unroll
  for (int mb = 0; mb < 2; ++mb)
#pragma unroll
    for (int nb = 0; nb < 4; ++nb)
#pragma unroll
      for (int rg = 0; rg < 4; ++rg) {
        int row = wave * 32 + mb * 16 + quad * 4 + rg;  // C/D: col=lane&15, row=quad*4+reg
        int r = m0 + row;
        if (r < cnt) {
          int n = n0 + nb * 16 + l16;
          float g = accg[mb][nb][rg] + gp_b[e * HID + n];
          float u = accu[mb][nb][rg] + up_b[e * HID + n];
          float sw = u / (1.f + expf(-u));
          h[(size_t)(offe + r) * HID + n] = (__bf16)(g * sw);
        }
      }
}

// FFN2: out[tok] += w * (h @ dp + b)
__global__ __launch_bounds__(256) void ffn2_kernel(
    const __bf16* __restrict__ h, const __bf16* __restrict__ dpb, const float* __restrict__ dp_b,
    const int* __restrict__ counts, const int* __restrict__ offsets,
    const int* __restrict__ tok_list, const float* __restrict__ tok_w,
    float* __restrict__ out)
{
  int e = blockIdx.z;
  int cnt = counts[e];
  int m0 = blockIdx.y * BM;
  if (m0 >= cnt) return;
  int n0 = blockIdx.x * BN;

  __shared__ __align__(16) __bf16 As[BM * LDSS];
  __shared__ __align__(16) __bf16 Bs[BN * LDSS];
  __shared__ int toks[BM];
  __shared__ float wts[BM];

  int tid = threadIdx.x;
  if (tid < BM) {
    int r = m0 + tid;
    bool v = r < cnt;
    toks[tid] = v ? tok_list[e * T_TOK + r] : 0;
    wts[tid]  = v ? tok_w[e * T_TOK + r] : 0.f;
  }

  int wave = tid >> 6, lane = tid & 63;
  int quad = lane >> 4, l16 = lane & 15;

  f32_4 acc[2][4];
  {
    f32_4 z = {0.f, 0.f, 0.f, 0.f};
#pragma unroll
    for (int a = 0; a < 2; ++a)
#pragma unroll
      for (int b = 0; b < 4; ++b) acc[a][b] = z;
  }

  const __bf16* Arows = h + (size_t)(offsets[e] + m0) * HID;
  const __bf16* Bd = dpb + ((size_t)e * DMODEL + n0) * HID;
  __syncthreads();

  for (int k0 = 0; k0 < HID; k0 += BK) {
#pragma unroll
    for (int c = 0; c < 2; ++c) {
      int idx = tid + c * 256;
      int r = idx >> 2, ko = (idx & 3) * 8;
      bf16_8 v = (m0 + r < cnt) ? *(const bf16_8*)(Arows + (size_t)r * HID + k0 + ko)
                                : zero_bf16_8();
      *(bf16_8*)(As + r * LDSS + ko) = v;
    }
    {
      int r = tid >> 2, ko = (tid & 3) * 8;
      *(bf16_8*)(Bs + r * LDSS + ko) = *(const bf16_8*)(Bd + (size_t)r * HID + k0 + ko);
    }
    __syncthreads();

    bf16_8 af[2];
#pragma unroll
    for (int mb = 0; mb < 2; ++mb)
      af[mb] = *(const bf16_8*)(As + (wave * 32 + mb * 16 + l16) * LDSS + quad * 8);
#pragma unroll
    for (int nb = 0; nb < 4; ++nb) {
      bf16_8 bb = *(const bf16_8*)(Bs + (nb * 16 + l16) * LDSS + quad * 8);
#pragma unroll
      for (int mb = 0; mb < 2; ++mb)
        acc[mb][nb] = __builtin_amdgcn_mfma_f32_16x16x32_bf16(af[mb], bb, acc[mb][nb], 0, 0, 0);
    }
    __syncthreads();
  }

#pragma unroll
  for (int mb = 0; mb < 2; ++mb)
#pragma unroll
    for (int nb = 0; nb < 4; ++nb)
#pragma unroll
      for (int rg = 0; rg < 4; ++rg) {
        int row = wave * 32 + mb * 16 + quad * 4 + rg;
        int r = m0 + row;
        if (r < cnt) {
          int n = n0 + nb * 16 + l16;
          float v = acc[mb][nb][rg] + dp_b[e * DMODEL + n];
          atomicAdd(&out[(size_t)toks[row] * DMODEL + n], wts[row] * v);
        }
      }
}

extern "C" void kernel_launch(void* const* d_in, const int* in_sizes, int n_in,
                              void* d_out, int out_size, void* d_ws, size_t ws_size,
                              hipStream_t stream)
{
  const float* x      = (const float*)d_in[0];
  const float* gate_w = (const float*)d_in[1];
  const float* gate_b = (const float*)d_in[2];
  const float* gp_w   = (const float*)d_in[3];
  const float* gp_b   = (const float*)d_in[4];
  const float* up_w   = (const float*)d_in[5];
  const float* up_b   = (const float*)d_in[6];
  const float* dp_w   = (const float*)d_in[7];
  const float* dp_b   = (const float*)d_in[8];

  char* ws = (char*)d_ws;
  size_t o = 0;
  __bf16* xb  = (__bf16*)(ws + o); o += (size_t)T_TOK * DMODEL * 2;          // 33.5 MB
  __bf16* gpb = (__bf16*)(ws + o); o += (size_t)NEXP * DMODEL * HID * 2;     // 16.8 MB
  __bf16* upb = (__bf16*)(ws + o); o += (size_t)NEXP * DMODEL * HID * 2;     // 16.8 MB
  __bf16* dpb = (__bf16*)(ws + o); o += (size_t)NEXP * HID * DMODEL * 2;     // 16.8 MB
  __bf16* hbuf = (__bf16*)(ws + o); o += (size_t)T_TOK * 2 * HID * 2;        // 33.5 MB
  int*   tok_list = (int*)(ws + o); o += (size_t)NEXP * T_TOK * 4;           // 1 MB
  float* tok_w    = (float*)(ws + o); o += (size_t)NEXP * T_TOK * 4;         // 1 MB
  int*   counts   = (int*)(ws + o); o += 64;
  int*   offsets  = (int*)(ws + o); o += 128;

  float* out = (float*)d_out;
  float* aux = out + (size_t)T_TOK * DMODEL;

  hipMemsetAsync(d_out, 0, (size_t)out_size * sizeof(float), stream);
  hipMemsetAsync(counts, 0, 192, stream);

  gate_kernel<<<T_TOK / 4, 256, 0, stream>>>(x, gate_w, gate_b, xb, counts, tok_list, tok_w);
  scan_kernel<<<1, 64, 0, stream>>>(counts, offsets, aux);
  transpose_bf16_kernel<DMODEL, HID><<<dim3(HID / 32, DMODEL / 32, NEXP), dim3(32, 8), 0, stream>>>(gp_w, gpb);
  transpose_bf16_kernel<DMODEL, HID><<<dim3(HID / 32, DMODEL / 32, NEXP), dim3(32, 8), 0, stream>>>(up_w, upb);
  transpose_bf16_kernel<HID, DMODEL><<<dim3(DMODEL / 32, HID / 32, NEXP), dim3(32, 8), 0, stream>>>(dp_w, dpb);
  ffn1_kernel<<<dim3(HID / BN, T_TOK / BM, NEXP), 256, 0, stream>>>(xb, gpb, upb, gp_b, up_b,
                                                                    counts, offsets, tok_list, hbuf);
  ffn2_kernel<<<dim3(DMODEL / BN, T_TOK / BM, NEXP), 256, 0, stream>>>(hbuf, dpb, dp_b,
                                                                       counts, offsets, tok_list, tok_w, out);
}

// Round 3
// 603.311 us; speedup vs baseline: 1.5179x; 1.5179x over previous
//
#include <hip/hip_runtime.h>
#include <hip/hip_bf16.h>
#include <math.h>

#define T_TOK 16384
#define DMODEL 1024
#define HID 512
#define NEXP 16
#define NASSIGN (T_TOK * 2)             // total (token, expert) pairs
#define HIST_BLK 64                     // blocks in hist/scatter phase
#define TOK_PER_BLK (T_TOK / HIST_BLK)  // 256

typedef __bf16 bf16_8 __attribute__((ext_vector_type(8)));
typedef float f32_4 __attribute__((ext_vector_type(4)));

__device__ inline bf16_8 zero_bf16_8() {
  bf16_8 v;
#pragma unroll
  for (int i = 0; i < 8; ++i) v[i] = (__bf16)0.f;
  return v;
}

// ---------------- gate compute: logits, softmax, top-2 -> per-token idx/w; x -> bf16. NO atomics ----------------
__global__ __launch_bounds__(256) void gate_compute_kernel(
    const float* __restrict__ x, const float* __restrict__ gw, const float* __restrict__ gb,
    __bf16* __restrict__ xb, int* __restrict__ topk_idx, float2* __restrict__ topk_w)
{
  int wave = threadIdx.x >> 6;
  int lane = threadIdx.x & 63;
  int t = blockIdx.x * 4 + wave;
  const float* xr = x + (size_t)t * DMODEL;
  float acc[NEXP];
#pragma unroll
  for (int e = 0; e < NEXP; ++e) acc[e] = 0.f;
  for (int i = lane; i < DMODEL; i += 64) {
    float xv = xr[i];
    xb[(size_t)t * DMODEL + i] = (__bf16)xv;
    const float* g = gw + (size_t)i * NEXP;
#pragma unroll
    for (int e = 0; e < NEXP; ++e) acc[e] = fmaf(xv, g[e], acc[e]);
  }
#pragma unroll
  for (int e = 0; e < NEXP; ++e) {
    float v = acc[e];
#pragma unroll
    for (int s = 32; s > 0; s >>= 1) v += __shfl_xor(v, s, 64);
    acc[e] = v;
  }
  if (lane == 0) {
    float mx = -1e30f;
#pragma unroll
    for (int e = 0; e < NEXP; ++e) { acc[e] += gb[e]; mx = fmaxf(mx, acc[e]); }
    float Z = 0.f;
#pragma unroll
    for (int e = 0; e < NEXP; ++e) { acc[e] = expf(acc[e] - mx); Z += acc[e]; }
    // top-2 (softmax monotonic in logits); strict > scan -> lowest index on ties, like lax.top_k
    int i0 = 0; float s0 = acc[0];
#pragma unroll
    for (int e = 1; e < NEXP; ++e) if (acc[e] > s0) { s0 = acc[e]; i0 = e; }
    int i1 = -1; float s1 = -1e30f;
#pragma unroll
    for (int e = 0; e < NEXP; ++e) if (e != i0 && acc[e] > s1) { s1 = acc[e]; i1 = e; }
    s0 /= Z; s1 /= Z;
    float dn = s0 + s1 + 1e-9f;
    topk_idx[t] = i0 | (i1 << 8);
    topk_w[t] = make_float2(s0 / dn, s1 / dn);
  }
}

// ---------------- per-block expert histogram (LDS atomics only) ----------------
__global__ __launch_bounds__(256) void hist_kernel(
    const int* __restrict__ topk_idx, int* __restrict__ block_hist)
{
  __shared__ int cnt[NEXP];
  int tid = threadIdx.x;
  if (tid < NEXP) cnt[tid] = 0;
  __syncthreads();
  int t = blockIdx.x * TOK_PER_BLK + tid;
  int p = topk_idx[t];
  atomicAdd(&cnt[p & 0xff], 1);
  atomicAdd(&cnt[p >> 8], 1);
  __syncthreads();
  if (tid < NEXP) block_hist[blockIdx.x * NEXP + tid] = cnt[tid];
}

// ---------------- scan: counts, offsets, per-block global bases, aux loss ----------------
__global__ void scan2_kernel(const int* __restrict__ block_hist,
                             int* __restrict__ counts, int* __restrict__ offsets,
                             int* __restrict__ block_base, float* __restrict__ aux_out)
{
  __shared__ int cl[NEXP];
  int lane = threadIdx.x;
  if (lane < NEXP) {
    int s = 0;
    for (int b = 0; b < HIST_BLK; ++b) s += block_hist[b * NEXP + lane];
    cl[lane] = s;
    counts[lane] = s;
  }
  __syncthreads();
  if (lane < NEXP) {
    int off = 0;
    for (int e = 0; e < lane; ++e) off += cl[e];
    offsets[lane] = off;
    int base = off;  // global compacted base for this expert, walked per block
    for (int b = 0; b < HIST_BLK; ++b) {
      block_base[b * NEXP + lane] = base;
      base += block_hist[b * NEXP + lane];
    }
  }
  if (lane == 0) {
    int tot = 0; float pen = 0.f;
    const float cap = 1.25f * (float)(T_TOK * 2) / (float)NEXP; // 2560
    for (int e = 0; e < NEXP; ++e) {
      tot += cl[e];
      float ld = (float)cl[e] - cap;
      pen += ld > 0.f ? ld : 0.f;
    }
    offsets[NEXP] = tot;
    aux_out[0] = 0.01f * pen / (float)NEXP / (float)T_TOK;
  }
}

// ---------------- scatter: compact-list positions via LDS atomics seeded from global block_base ----------------
__global__ __launch_bounds__(256) void scatter_kernel(
    const int* __restrict__ topk_idx, const float2* __restrict__ topk_w,
    const int* __restrict__ block_base,
    int* __restrict__ tok_list, float* __restrict__ tok_w)
{
  __shared__ int base[NEXP];
  int tid = threadIdx.x;
  if (tid < NEXP) base[tid] = block_base[blockIdx.x * NEXP + tid];
  __syncthreads();
  int t = blockIdx.x * TOK_PER_BLK + tid;
  int p = topk_idx[t];
  float2 w = topk_w[t];
  int i0 = p & 0xff, i1 = p >> 8;
  int p0 = atomicAdd(&base[i0], 1);   // p0 is a GLOBAL compacted slot
  tok_list[p0] = t; tok_w[p0] = w.x;
  int p1 = atomicAdd(&base[i1], 1);
  tok_list[p1] = t; tok_w[p1] = w.y;
}

// ---------------- tiled transpose fp32[E][R][C] -> bf16[E][C][R] ----------------
template<int R, int C>
__global__ __launch_bounds__(256) void transpose_bf16_kernel(const float* __restrict__ in,
                                                             __bf16* __restrict__ out)
{
  __shared__ float tile[32][33];
  int e = blockIdx.z;
  int c0 = blockIdx.x * 32, r0 = blockIdx.y * 32;
  const float* src = in + ((size_t)e * R + r0) * C + c0;
#pragma unroll
  for (int i = 0; i < 4; ++i) {
    int r = threadIdx.y + i * 8;
    tile[r][threadIdx.x] = src[(size_t)r * C + threadIdx.x];
  }
  __syncthreads();
  __bf16* dst = out + ((size_t)e * C + c0) * R + r0;
#pragma unroll
  for (int i = 0; i < 4; ++i) {
    int c = threadIdx.y + i * 8;
    dst[(size_t)c * R + threadIdx.x] = (__bf16)tile[threadIdx.x][c];
  }
}

// ---------------- grouped GEMM tiles ----------------
#define BM 128
#define BN 64
#define BK 32
#define LDSS 40  // bf16 elements per LDS row (pad: 80B stride -> <=2-way bank alias, free)

// FFN1: h = (x@gp + b) * silu(x@up + b), per (expert, token-slot). A gathered via compact tok_list.
__global__ __launch_bounds__(256) void ffn1_kernel(
    const __bf16* __restrict__ xb, const __bf16* __restrict__ gpb, const __bf16* __restrict__ upb,
    const float* __restrict__ gp_b, const float* __restrict__ up_b,
    const int* __restrict__ counts, const int* __restrict__ offsets,
    const int* __restrict__ tok_list, __bf16* __restrict__ h)
{
  int e = blockIdx.z;
  int cnt = counts[e];
  int m0 = blockIdx.y * BM;
  if (m0 >= cnt) return;
  int n0 = blockIdx.x * BN;
  int offe = offsets[e];

  __shared__ __align__(16) __bf16 As[BM * LDSS];
  __shared__ __align__(16) __bf16 Bgs[BN * LDSS];
  __shared__ __align__(16) __bf16 Bus[BN * LDSS];
  __shared__ int toks[BM];

  int tid = threadIdx.x;
  if (tid < BM) {
    int r = m0 + tid;
    toks[tid] = (r < cnt) ? tok_list[offe + r] : -1;
  }

  int wave = tid >> 6, lane = tid & 63;
  int quad = lane >> 4, l16 = lane & 15;

  f32_4 accg[2][4], accu[2][4];
  {
    f32_4 z = {0.f, 0.f, 0.f, 0.f};
#pragma unroll
    for (int a = 0; a < 2; ++a)
#pragma unroll
      for (int b = 0; b < 4; ++b) { accg[a][b] = z; accu[a][b] = z; }
  }

  const __bf16* Bg = gpb + ((size_t)e * HID + n0) * DMODEL;
  const __bf16* Bu = upb + ((size_t)e * HID + n0) * DMODEL;
  __syncthreads();

  for (int k0 = 0; k0 < DMODEL; k0 += BK) {
#pragma unroll
    for (int c = 0; c < 2; ++c) {
      int idx = tid + c * 256;
      int r = idx >> 2, ko = (idx & 3) * 8;
      int t = toks[r];
      bf16_8 v = (t >= 0) ? *(const bf16_8*)(xb + (size_t)t * DMODEL + k0 + ko) : zero_bf16_8();
      *(bf16_8*)(As + r * LDSS + ko) = v;
    }
    {
      int r = tid >> 2, ko = (tid & 3) * 8;
      *(bf16_8*)(Bgs + r * LDSS + ko) = *(const bf16_8*)(Bg + (size_t)r * DMODEL + k0 + ko);
      *(bf16_8*)(Bus + r * LDSS + ko) = *(const bf16_8*)(Bu + (size_t)r * DMODEL + k0 + ko);
    }
    __syncthreads();

    bf16_8 af[2];
#pragma unroll
    for (int mb = 0; mb < 2; ++mb)
      af[mb] = *(const bf16_8*)(As + (wave * 32 + mb * 16 + l16) * LDSS + quad * 8);
#pragma unroll
    for (int nb = 0; nb < 4; ++nb) {
      bf16_8 bg = *(const bf16_8*)(Bgs + (nb * 16 + l16) * LDSS + quad * 8);
      bf16_8 bu = *(const bf16_8*)(Bus + (nb * 16 + l16) * LDSS + quad * 8);
#pragma unroll
      for (int mb = 0; mb < 2; ++mb) {
        accg[mb][nb] = __builtin_amdgcn_mfma_f32_16x16x32_bf16(af[mb], bg, accg[mb][nb], 0, 0, 0);
        accu[mb][nb] = __builtin_amdgcn_mfma_f32_16x16x32_bf16(af[mb], bu, accu[mb][nb], 0, 0, 0);
      }
    }
    __syncthreads();
  }

#pragma unroll
  for (int mb = 0; mb < 2; ++mb)
#pragma unroll
    for (int nb = 0; nb < 4; ++nb)
#pragma unroll
      for (int rg = 0; rg < 4; ++rg) {
        int row = wave * 32 + mb * 16 + quad * 4 + rg;  // C/D: col=lane&15, row=quad*4+reg
        int r = m0 + row;
        if (r < cnt) {
          int n = n0 + nb * 16 + l16;
          float g = accg[mb][nb][rg] + gp_b[e * HID + n];
          float u = accu[mb][nb][rg] + up_b[e * HID + n];
          float sw = u / (1.f + expf(-u));
          h[(size_t)(offe + r) * HID + n] = (__bf16)(g * sw);
        }
      }
}

// FFN2: out[tok] += w * (h @ dp + b)
__global__ __launch_bounds__(256) void ffn2_kernel(
    const __bf16* __restrict__ h, const __bf16* __restrict__ dpb, const float* __restrict__ dp_b,
    const int* __restrict__ counts, const int* __restrict__ offsets,
    const int* __restrict__ tok_list, const float* __restrict__ tok_w,
    float* __restrict__ out)
{
  int e = blockIdx.z;
  int cnt = counts[e];
  int m0 = blockIdx.y * BM;
  if (m0 >= cnt) return;
  int n0 = blockIdx.x * BN;
  int offe = offsets[e];

  __shared__ __align__(16) __bf16 As[BM * LDSS];
  __shared__ __align__(16) __bf16 Bs[BN * LDSS];
  __shared__ int toks[BM];
  __shared__ float wts[BM];

  int tid = threadIdx.x;
  if (tid < BM) {
    int r = m0 + tid;
    bool v = r < cnt;
    toks[tid] = v ? tok_list[offe + r] : 0;
    wts[tid]  = v ? tok_w[offe + r] : 0.f;
  }

  int wave = tid >> 6, lane = tid & 63;
  int quad = lane >> 4, l16 = lane & 15;

  f32_4 acc[2][4];
  {
    f32_4 z = {0.f, 0.f, 0.f, 0.f};
#pragma unroll
    for (int a = 0; a < 2; ++a)
#pragma unroll
      for (int b = 0; b < 4; ++b) acc[a][b] = z;
  }

  const __bf16* Arows = h + (size_t)(offe + m0) * HID;
  const __bf16* Bd = dpb + ((size_t)e * DMODEL + n0) * HID;
  __syncthreads();

  for (int k0 = 0; k0 < HID; k0 += BK) {
#pragma unroll
    for (int c = 0; c < 2; ++c) {
      int idx = tid + c * 256;
      int r = idx >> 2, ko = (idx & 3) * 8;
      bf16_8 v = (m0 + r < cnt) ? *(const bf16_8*)(Arows + (size_t)r * HID + k0 + ko)
                                : zero_bf16_8();
      *(bf16_8*)(As + r * LDSS + ko) = v;
    }
    {
      int r = tid >> 2, ko = (tid & 3) * 8;
      *(bf16_8*)(Bs + r * LDSS + ko) = *(const bf16_8*)(Bd + (size_t)r * HID + k0 + ko);
    }
    __syncthreads();

    bf16_8 af[2];
#pragma unroll
    for (int mb = 0; mb < 2; ++mb)
      af[mb] = *(const bf16_8*)(As + (wave * 32 + mb * 16 + l16) * LDSS + quad * 8);
#pragma unroll
    for (int nb = 0; nb < 4; ++nb) {
      bf16_8 bb = *(const bf16_8*)(Bs + (nb * 16 + l16) * LDSS + quad * 8);
#pragma unroll
      for (int mb = 0; mb < 2; ++mb)
        acc[mb][nb] = __builtin_amdgcn_mfma_f32_16x16x32_bf16(af[mb], bb, acc[mb][nb], 0, 0, 0);
    }
    __syncthreads();
  }

#pragma unroll
  for (int mb = 0; mb < 2; ++mb)
#pragma unroll
    for (int nb = 0; nb < 4; ++nb)
#pragma unroll
      for (int rg = 0; rg < 4; ++rg) {
        int row = wave * 32 + mb * 16 + quad * 4 + rg;
        int r = m0 + row;
        if (r < cnt) {
          int n = n0 + nb * 16 + l16;
          float v = acc[mb][nb][rg] + dp_b[e * DMODEL + n];
          atomicAdd(&out[(size_t)toks[row] * DMODEL + n], wts[row] * v);
        }
      }
}

extern "C" void kernel_launch(void* const* d_in, const int* in_sizes, int n_in,
                              void* d_out, int out_size, void* d_ws, size_t ws_size,
                              hipStream_t stream)
{
  const float* x      = (const float*)d_in[0];
  const float* gate_w = (const float*)d_in[1];
  const float* gate_b = (const float*)d_in[2];
  const float* gp_w   = (const float*)d_in[3];
  const float* gp_b   = (const float*)d_in[4];
  const float* up_w   = (const float*)d_in[5];
  const float* up_b   = (const float*)d_in[6];
  const float* dp_w   = (const float*)d_in[7];
  const float* dp_b   = (const float*)d_in[8];

  // Workspace layout — total ~117.8 MB (below the 119.6 MB watermark proven safe in R1)
  char* ws = (char*)d_ws;
  size_t o = 0;
  __bf16* xb  = (__bf16*)(ws + o); o += (size_t)T_TOK * DMODEL * 2;          // 33.55 MB
  __bf16* gpb = (__bf16*)(ws + o); o += (size_t)NEXP * DMODEL * HID * 2;     // 16.78 MB
  __bf16* upb = (__bf16*)(ws + o); o += (size_t)NEXP * DMODEL * HID * 2;     // 16.78 MB
  __bf16* dpb = (__bf16*)(ws + o); o += (size_t)NEXP * HID * DMODEL * 2;     // 16.78 MB
  __bf16* hbuf = (__bf16*)(ws + o); o += (size_t)NASSIGN * HID * 2;          // 33.55 MB
  int*   tok_list = (int*)(ws + o); o += (size_t)NASSIGN * 4;                // 128 KB (compact)
  float* tok_w    = (float*)(ws + o); o += (size_t)NASSIGN * 4;              // 128 KB (compact)
  int*   topk_idx = (int*)(ws + o); o += (size_t)T_TOK * 4;                  // 64 KB
  float2* topk_w  = (float2*)(ws + o); o += (size_t)T_TOK * 8;               // 128 KB
  int*   block_hist = (int*)(ws + o); o += (size_t)HIST_BLK * NEXP * 4;      // 4 KB
  int*   block_base = (int*)(ws + o); o += (size_t)HIST_BLK * NEXP * 4;      // 4 KB
  int*   counts   = (int*)(ws + o); o += 64;
  int*   offsets  = (int*)(ws + o); o += 128;

  float* out = (float*)d_out;
  float* aux = out + (size_t)T_TOK * DMODEL;

  hipMemsetAsync(d_out, 0, (size_t)out_size * sizeof(float), stream);

  gate_compute_kernel<<<T_TOK / 4, 256, 0, stream>>>(x, gate_w, gate_b, xb, topk_idx, topk_w);
  hist_kernel<<<HIST_BLK, TOK_PER_BLK, 0, stream>>>(topk_idx, block_hist);
  scan2_kernel<<<1, 64, 0, stream>>>(block_hist, counts, offsets, block_base, aux);
  scatter_kernel<<<HIST_BLK, TOK_PER_BLK, 0, stream>>>(topk_idx, topk_w, block_base, tok_list, tok_w);
  transpose_bf16_kernel<DMODEL, HID><<<dim3(HID / 32, DMODEL / 32, NEXP), dim3(32, 8), 0, stream>>>(gp_w, gpb);
  transpose_bf16_kernel<DMODEL, HID><<<dim3(HID / 32, DMODEL / 32, NEXP), dim3(32, 8), 0, stream>>>(up_w, upb);
  transpose_bf16_kernel<HID, DMODEL><<<dim3(DMODEL / 32, HID / 32, NEXP), dim3(32, 8), 0, stream>>>(dp_w, dpb);
  ffn1_kernel<<<dim3(HID / BN, T_TOK / BM, NEXP), 256, 0, stream>>>(xb, gpb, upb, gp_b, up_b,
                                                                    counts, offsets, tok_list, hbuf);
  ffn2_kernel<<<dim3(DMODEL / BN, T_TOK / BM, NEXP), 256, 0, stream>>>(hbuf, dpb, dp_b,
                                                                       counts, offsets, tok_list, tok_w, out);
}

// Round 4
// 539.539 us; speedup vs baseline: 1.6973x; 1.1182x over previous
//
#include <hip/hip_runtime.h>
#include <hip/hip_bf16.h>
#include <math.h>

#define T_TOK 16384
#define DMODEL 1024
#define HID 512
#define NEXP 16
#define NASSIGN (T_TOK * 2)             // total (token, expert) pairs
#define HIST_BLK 64                     // blocks in hist/scatter phase
#define TOK_PER_BLK (T_TOK / HIST_BLK)  // 256

typedef __bf16 bf16_8 __attribute__((ext_vector_type(8)));
typedef float f32_4 __attribute__((ext_vector_type(4)));

__device__ inline bf16_8 zero_bf16_8() {
  bf16_8 v;
#pragma unroll
  for (int i = 0; i < 8; ++i) v[i] = (__bf16)0.f;
  return v;
}

// ---------------- gate compute: logits, softmax, top-2 -> per-token idx/w; x -> bf16. NO atomics ----------------
__global__ __launch_bounds__(256) void gate_compute_kernel(
    const float* __restrict__ x, const float* __restrict__ gw, const float* __restrict__ gb,
    __bf16* __restrict__ xb, int* __restrict__ topk_idx, float2* __restrict__ topk_w)
{
  int wave = threadIdx.x >> 6;
  int lane = threadIdx.x & 63;
  int t = blockIdx.x * 4 + wave;
  const float* xr = x + (size_t)t * DMODEL;
  float acc[NEXP];
#pragma unroll
  for (int e = 0; e < NEXP; ++e) acc[e] = 0.f;
  for (int i = lane; i < DMODEL; i += 64) {
    float xv = xr[i];
    xb[(size_t)t * DMODEL + i] = (__bf16)xv;
    const float* g = gw + (size_t)i * NEXP;
#pragma unroll
    for (int e = 0; e < NEXP; ++e) acc[e] = fmaf(xv, g[e], acc[e]);
  }
#pragma unroll
  for (int e = 0; e < NEXP; ++e) {
    float v = acc[e];
#pragma unroll
    for (int s = 32; s > 0; s >>= 1) v += __shfl_xor(v, s, 64);
    acc[e] = v;
  }
  if (lane == 0) {
    float mx = -1e30f;
#pragma unroll
    for (int e = 0; e < NEXP; ++e) { acc[e] += gb[e]; mx = fmaxf(mx, acc[e]); }
    float Z = 0.f;
#pragma unroll
    for (int e = 0; e < NEXP; ++e) { acc[e] = expf(acc[e] - mx); Z += acc[e]; }
    // top-2 (softmax monotonic in logits); strict > scan -> lowest index on ties, like lax.top_k
    int i0 = 0; float s0 = acc[0];
#pragma unroll
    for (int e = 1; e < NEXP; ++e) if (acc[e] > s0) { s0 = acc[e]; i0 = e; }
    int i1 = -1; float s1 = -1e30f;
#pragma unroll
    for (int e = 0; e < NEXP; ++e) if (e != i0 && acc[e] > s1) { s1 = acc[e]; i1 = e; }
    s0 /= Z; s1 /= Z;
    float dn = s0 + s1 + 1e-9f;
    topk_idx[t] = i0 | (i1 << 8);
    topk_w[t] = make_float2(s0 / dn, s1 / dn);
  }
}

// ---------------- per-block expert histogram (LDS atomics only) ----------------
__global__ __launch_bounds__(256) void hist_kernel(
    const int* __restrict__ topk_idx, int* __restrict__ block_hist)
{
  __shared__ int cnt[NEXP];
  int tid = threadIdx.x;
  if (tid < NEXP) cnt[tid] = 0;
  __syncthreads();
  int t = blockIdx.x * TOK_PER_BLK + tid;
  int p = topk_idx[t];
  atomicAdd(&cnt[p & 0xff], 1);
  atomicAdd(&cnt[p >> 8], 1);
  __syncthreads();
  if (tid < NEXP) block_hist[blockIdx.x * NEXP + tid] = cnt[tid];
}

// ---------------- scan: counts, offsets, per-block global bases, aux loss ----------------
__global__ void scan2_kernel(const int* __restrict__ block_hist,
                             int* __restrict__ counts, int* __restrict__ offsets,
                             int* __restrict__ block_base, float* __restrict__ aux_out)
{
  __shared__ int cl[NEXP];
  int lane = threadIdx.x;
  if (lane < NEXP) {
    int s = 0;
    for (int b = 0; b < HIST_BLK; ++b) s += block_hist[b * NEXP + lane];
    cl[lane] = s;
    counts[lane] = s;
  }
  __syncthreads();
  if (lane < NEXP) {
    int off = 0;
    for (int e = 0; e < lane; ++e) off += cl[e];
    offsets[lane] = off;
    int base = off;  // global compacted base for this expert, walked per block
    for (int b = 0; b < HIST_BLK; ++b) {
      block_base[b * NEXP + lane] = base;
      base += block_hist[b * NEXP + lane];
    }
  }
  if (lane == 0) {
    int tot = 0; float pen = 0.f;
    const float cap = 1.25f * (float)(T_TOK * 2) / (float)NEXP; // 2560
    for (int e = 0; e < NEXP; ++e) {
      tot += cl[e];
      float ld = (float)cl[e] - cap;
      pen += ld > 0.f ? ld : 0.f;
    }
    offsets[NEXP] = tot;
    aux_out[0] = 0.01f * pen / (float)NEXP / (float)T_TOK;
  }
}

// ---------------- scatter: compact-list positions + inverse map (token -> slots) ----------------
__global__ __launch_bounds__(256) void scatter_kernel(
    const int* __restrict__ topk_idx, const int* __restrict__ block_base,
    int* __restrict__ tok_list, int2* __restrict__ tok_slots)
{
  __shared__ int base[NEXP];
  int tid = threadIdx.x;
  if (tid < NEXP) base[tid] = block_base[blockIdx.x * NEXP + tid];
  __syncthreads();
  int t = blockIdx.x * TOK_PER_BLK + tid;
  int p = topk_idx[t];
  int i0 = p & 0xff, i1 = p >> 8;
  int p0 = atomicAdd(&base[i0], 1);   // GLOBAL compacted slot
  tok_list[p0] = t;
  int p1 = atomicAdd(&base[i1], 1);
  tok_list[p1] = t;
  tok_slots[t] = make_int2(p0, p1);
}

// ---------------- tiled transpose fp32[E][R][C] -> bf16[E][C][R] ----------------
template<int R, int C>
__global__ __launch_bounds__(256) void transpose_bf16_kernel(const float* __restrict__ in,
                                                             __bf16* __restrict__ out)
{
  __shared__ float tile[32][33];
  int e = blockIdx.z;
  int c0 = blockIdx.x * 32, r0 = blockIdx.y * 32;
  const float* src = in + ((size_t)e * R + r0) * C + c0;
#pragma unroll
  for (int i = 0; i < 4; ++i) {
    int r = threadIdx.y + i * 8;
    tile[r][threadIdx.x] = src[(size_t)r * C + threadIdx.x];
  }
  __syncthreads();
  __bf16* dst = out + ((size_t)e * C + c0) * R + r0;
#pragma unroll
  for (int i = 0; i < 4; ++i) {
    int c = threadIdx.y + i * 8;
    dst[(size_t)c * R + threadIdx.x] = (__bf16)tile[threadIdx.x][c];
  }
}

// ---------------- grouped GEMM tiles ----------------
#define BM 128
#define BN 64
#define BK 32
#define LDSS 40  // bf16 elements per LDS row (pad: 80B stride -> <=2-way bank alias, free)

// FFN1: h = (x@gp + b) * silu(x@up + b), per (expert, token-slot). A gathered via compact tok_list.
__global__ __launch_bounds__(256) void ffn1_kernel(
    const __bf16* __restrict__ xb, const __bf16* __restrict__ gpb, const __bf16* __restrict__ upb,
    const float* __restrict__ gp_b, const float* __restrict__ up_b,
    const int* __restrict__ counts, const int* __restrict__ offsets,
    const int* __restrict__ tok_list, __bf16* __restrict__ h)
{
  int e = blockIdx.z;
  int cnt = counts[e];
  int m0 = blockIdx.y * BM;
  if (m0 >= cnt) return;
  int n0 = blockIdx.x * BN;
  int offe = offsets[e];

  __shared__ __align__(16) __bf16 As[BM * LDSS];
  __shared__ __align__(16) __bf16 Bgs[BN * LDSS];
  __shared__ __align__(16) __bf16 Bus[BN * LDSS];
  __shared__ int toks[BM];

  int tid = threadIdx.x;
  if (tid < BM) {
    int r = m0 + tid;
    toks[tid] = (r < cnt) ? tok_list[offe + r] : -1;
  }

  int wave = tid >> 6, lane = tid & 63;
  int quad = lane >> 4, l16 = lane & 15;

  f32_4 accg[2][4], accu[2][4];
  {
    f32_4 z = {0.f, 0.f, 0.f, 0.f};
#pragma unroll
    for (int a = 0; a < 2; ++a)
#pragma unroll
      for (int b = 0; b < 4; ++b) { accg[a][b] = z; accu[a][b] = z; }
  }

  const __bf16* Bg = gpb + ((size_t)e * HID + n0) * DMODEL;
  const __bf16* Bu = upb + ((size_t)e * HID + n0) * DMODEL;
  __syncthreads();

  for (int k0 = 0; k0 < DMODEL; k0 += BK) {
#pragma unroll
    for (int c = 0; c < 2; ++c) {
      int idx = tid + c * 256;
      int r = idx >> 2, ko = (idx & 3) * 8;
      int t = toks[r];
      bf16_8 v = (t >= 0) ? *(const bf16_8*)(xb + (size_t)t * DMODEL + k0 + ko) : zero_bf16_8();
      *(bf16_8*)(As + r * LDSS + ko) = v;
    }
    {
      int r = tid >> 2, ko = (tid & 3) * 8;
      *(bf16_8*)(Bgs + r * LDSS + ko) = *(const bf16_8*)(Bg + (size_t)r * DMODEL + k0 + ko);
      *(bf16_8*)(Bus + r * LDSS + ko) = *(const bf16_8*)(Bu + (size_t)r * DMODEL + k0 + ko);
    }
    __syncthreads();

    bf16_8 af[2];
#pragma unroll
    for (int mb = 0; mb < 2; ++mb)
      af[mb] = *(const bf16_8*)(As + (wave * 32 + mb * 16 + l16) * LDSS + quad * 8);
#pragma unroll
    for (int nb = 0; nb < 4; ++nb) {
      bf16_8 bg = *(const bf16_8*)(Bgs + (nb * 16 + l16) * LDSS + quad * 8);
      bf16_8 bu = *(const bf16_8*)(Bus + (nb * 16 + l16) * LDSS + quad * 8);
#pragma unroll
      for (int mb = 0; mb < 2; ++mb) {
        accg[mb][nb] = __builtin_amdgcn_mfma_f32_16x16x32_bf16(af[mb], bg, accg[mb][nb], 0, 0, 0);
        accu[mb][nb] = __builtin_amdgcn_mfma_f32_16x16x32_bf16(af[mb], bu, accu[mb][nb], 0, 0, 0);
      }
    }
    __syncthreads();
  }

#pragma unroll
  for (int mb = 0; mb < 2; ++mb)
#pragma unroll
    for (int nb = 0; nb < 4; ++nb)
#pragma unroll
      for (int rg = 0; rg < 4; ++rg) {
        int row = wave * 32 + mb * 16 + quad * 4 + rg;  // C/D: col=lane&15, row=quad*4+reg
        int r = m0 + row;
        if (r < cnt) {
          int n = n0 + nb * 16 + l16;
          float g = accg[mb][nb][rg] + gp_b[e * HID + n];
          float u = accu[mb][nb][rg] + up_b[e * HID + n];
          float sw = u / (1.f + expf(-u));
          h[(size_t)(offe + r) * HID + n] = (__bf16)(g * sw);
        }
      }
}

// FFN2: ybuf[slot] = h[slot] @ dp + b   (coalesced bf16 stores, NO atomics)
__global__ __launch_bounds__(256) void ffn2_kernel(
    const __bf16* __restrict__ h, const __bf16* __restrict__ dpb, const float* __restrict__ dp_b,
    const int* __restrict__ counts, const int* __restrict__ offsets,
    __bf16* __restrict__ ybuf)
{
  int e = blockIdx.z;
  int cnt = counts[e];
  int m0 = blockIdx.y * BM;
  if (m0 >= cnt) return;
  int n0 = blockIdx.x * BN;
  int offe = offsets[e];

  __shared__ __align__(16) __bf16 As[BM * LDSS];
  __shared__ __align__(16) __bf16 Bs[BN * LDSS];

  int tid = threadIdx.x;
  int wave = tid >> 6, lane = tid & 63;
  int quad = lane >> 4, l16 = lane & 15;

  f32_4 acc[2][4];
  {
    f32_4 z = {0.f, 0.f, 0.f, 0.f};
#pragma unroll
    for (int a = 0; a < 2; ++a)
#pragma unroll
      for (int b = 0; b < 4; ++b) acc[a][b] = z;
  }

  const __bf16* Arows = h + (size_t)(offe + m0) * HID;
  const __bf16* Bd = dpb + ((size_t)e * DMODEL + n0) * HID;

  for (int k0 = 0; k0 < HID; k0 += BK) {
#pragma unroll
    for (int c = 0; c < 2; ++c) {
      int idx = tid + c * 256;
      int r = idx >> 2, ko = (idx & 3) * 8;
      bf16_8 v = (m0 + r < cnt) ? *(const bf16_8*)(Arows + (size_t)r * HID + k0 + ko)
                                : zero_bf16_8();
      *(bf16_8*)(As + r * LDSS + ko) = v;
    }
    {
      int r = tid >> 2, ko = (tid & 3) * 8;
      *(bf16_8*)(Bs + r * LDSS + ko) = *(const bf16_8*)(Bd + (size_t)r * HID + k0 + ko);
    }
    __syncthreads();

    bf16_8 af[2];
#pragma unroll
    for (int mb = 0; mb < 2; ++mb)
      af[mb] = *(const bf16_8*)(As + (wave * 32 + mb * 16 + l16) * LDSS + quad * 8);
#pragma unroll
    for (int nb = 0; nb < 4; ++nb) {
      bf16_8 bb = *(const bf16_8*)(Bs + (nb * 16 + l16) * LDSS + quad * 8);
#pragma unroll
      for (int mb = 0; mb < 2; ++mb)
        acc[mb][nb] = __builtin_amdgcn_mfma_f32_16x16x32_bf16(af[mb], bb, acc[mb][nb], 0, 0, 0);
    }
    __syncthreads();
  }

#pragma unroll
  for (int mb = 0; mb < 2; ++mb)
#pragma unroll
    for (int nb = 0; nb < 4; ++nb)
#pragma unroll
      for (int rg = 0; rg < 4; ++rg) {
        int row = wave * 32 + mb * 16 + quad * 4 + rg;
        int r = m0 + row;
        if (r < cnt) {
          int n = n0 + nb * 16 + l16;
          float v = acc[mb][nb][rg] + dp_b[e * DMODEL + n];
          ybuf[(size_t)(offe + r) * DMODEL + n] = (__bf16)v;
        }
      }
}

// ---------------- combine: out[t] = w0*y[slot0] + w1*y[slot1] ----------------
// 256 threads = 2 tokens/block (128 threads x 8 elems = 1024 dims)
__global__ __launch_bounds__(256) void combine_kernel(
    const __bf16* __restrict__ ybuf, const int2* __restrict__ tok_slots,
    const float2* __restrict__ topk_w, float* __restrict__ out)
{
  int tid = threadIdx.x;
  int t = blockIdx.x * 2 + (tid >> 7);
  int d = (tid & 127) * 8;
  int2 sl = tok_slots[t];
  float2 w = topk_w[t];
  bf16_8 y0 = *(const bf16_8*)(ybuf + (size_t)sl.x * DMODEL + d);
  bf16_8 y1 = *(const bf16_8*)(ybuf + (size_t)sl.y * DMODEL + d);
  float* o = out + (size_t)t * DMODEL + d;
  f32_4 r0, r1;
#pragma unroll
  for (int i = 0; i < 4; ++i) r0[i] = w.x * (float)y0[i] + w.y * (float)y1[i];
#pragma unroll
  for (int i = 0; i < 4; ++i) r1[i] = w.x * (float)y0[4 + i] + w.y * (float)y1[4 + i];
  *(f32_4*)o = r0;
  *(f32_4*)(o + 4) = r1;
}

extern "C" void kernel_launch(void* const* d_in, const int* in_sizes, int n_in,
                              void* d_out, int out_size, void* d_ws, size_t ws_size,
                              hipStream_t stream)
{
  const float* x      = (const float*)d_in[0];
  const float* gate_w = (const float*)d_in[1];
  const float* gate_b = (const float*)d_in[2];
  const float* gp_w   = (const float*)d_in[3];
  const float* gp_b   = (const float*)d_in[4];
  const float* up_w   = (const float*)d_in[5];
  const float* up_b   = (const float*)d_in[6];
  const float* dp_w   = (const float*)d_in[7];
  const float* dp_b   = (const float*)d_in[8];

  // Workspace layout — total ~118 MB (below the 119.6 MB watermark proven safe in R1).
  // ybuf (67.1 MB) aliases xb+gpb+upb, which are dead once ffn1 completes.
  char* ws = (char*)d_ws;
  size_t o = 0;
  __bf16* xb  = (__bf16*)(ws + o); o += (size_t)T_TOK * DMODEL * 2;          // 33.55 MB
  __bf16* gpb = (__bf16*)(ws + o); o += (size_t)NEXP * DMODEL * HID * 2;     // 16.78 MB
  __bf16* upb = (__bf16*)(ws + o); o += (size_t)NEXP * DMODEL * HID * 2;     // 16.78 MB
  __bf16* dpb = (__bf16*)(ws + o); o += (size_t)NEXP * HID * DMODEL * 2;     // 16.78 MB
  __bf16* hbuf = (__bf16*)(ws + o); o += (size_t)NASSIGN * HID * 2;          // 33.55 MB
  int*   tok_list = (int*)(ws + o); o += (size_t)NASSIGN * 4;                // 128 KB (compact)
  int2*  tok_slots = (int2*)(ws + o); o += (size_t)T_TOK * 8;                // 128 KB
  int*   topk_idx = (int*)(ws + o); o += (size_t)T_TOK * 4;                  // 64 KB
  float2* topk_w  = (float2*)(ws + o); o += (size_t)T_TOK * 8;               // 128 KB
  int*   block_hist = (int*)(ws + o); o += (size_t)HIST_BLK * NEXP * 4;      // 4 KB
  int*   block_base = (int*)(ws + o); o += (size_t)HIST_BLK * NEXP * 4;      // 4 KB
  int*   counts   = (int*)(ws + o); o += 64;
  int*   offsets  = (int*)(ws + o); o += 128;
  __bf16* ybuf = (__bf16*)ws;  // [NASSIGN][DMODEL] bf16 = 67.1 MB, aliases xb/gpb/upb

  float* out = (float*)d_out;
  float* aux = out + (size_t)T_TOK * DMODEL;

  gate_compute_kernel<<<T_TOK / 4, 256, 0, stream>>>(x, gate_w, gate_b, xb, topk_idx, topk_w);
  hist_kernel<<<HIST_BLK, TOK_PER_BLK, 0, stream>>>(topk_idx, block_hist);
  scan2_kernel<<<1, 64, 0, stream>>>(block_hist, counts, offsets, block_base, aux);
  scatter_kernel<<<HIST_BLK, TOK_PER_BLK, 0, stream>>>(topk_idx, block_base, tok_list, tok_slots);
  transpose_bf16_kernel<DMODEL, HID><<<dim3(HID / 32, DMODEL / 32, NEXP), dim3(32, 8), 0, stream>>>(gp_w, gpb);
  transpose_bf16_kernel<DMODEL, HID><<<dim3(HID / 32, DMODEL / 32, NEXP), dim3(32, 8), 0, stream>>>(up_w, upb);
  transpose_bf16_kernel<HID, DMODEL><<<dim3(DMODEL / 32, HID / 32, NEXP), dim3(32, 8), 0, stream>>>(dp_w, dpb);
  ffn1_kernel<<<dim3(HID / BN, T_TOK / BM, NEXP), 256, 0, stream>>>(xb, gpb, upb, gp_b, up_b,
                                                                    counts, offsets, tok_list, hbuf);
  ffn2_kernel<<<dim3(DMODEL / BN, T_TOK / BM, NEXP), 256, 0, stream>>>(hbuf, dpb, dp_b,
                                                                       counts, offsets, ybuf);
  combine_kernel<<<T_TOK / 2, 256, 0, stream>>>(ybuf, tok_slots, topk_w, out);
}

// Round 5
// 498.145 us; speedup vs baseline: 1.8384x; 1.0831x over previous
//
#include <hip/hip_runtime.h>
#include <hip/hip_bf16.h>
#include <math.h>

#define T_TOK 16384
#define DMODEL 1024
#define HID 512
#define NEXP 16
#define NASSIGN (T_TOK * 2)             // total (token, expert) pairs
#define HIST_BLK 64                     // blocks in hist/scatter phase
#define TOK_PER_BLK (T_TOK / HIST_BLK)  // 256

typedef __bf16 bf16_8 __attribute__((ext_vector_type(8)));
typedef float f32_4 __attribute__((ext_vector_type(4)));

// Async global->LDS, 16B per lane. LDS dest is wave-uniform base + lane*16,
// which matches our "idx = tid" contiguous chunk order with UNPADDED LDS rows.
__device__ __forceinline__ void gload16(const __bf16* g, __bf16* l) {
  __builtin_amdgcn_global_load_lds(
      (const __attribute__((address_space(1))) void*)g,
      (__attribute__((address_space(3))) void*)l, 16, 0, 0);
}

// ---------------- gate compute: logits, softmax, top-2 -> per-token idx/w; x -> bf16. NO atomics ----------------
__global__ __launch_bounds__(256) void gate_compute_kernel(
    const float* __restrict__ x, const float* __restrict__ gw, const float* __restrict__ gb,
    __bf16* __restrict__ xb, int* __restrict__ topk_idx, float2* __restrict__ topk_w)
{
  int wave = threadIdx.x >> 6;
  int lane = threadIdx.x & 63;
  int t = blockIdx.x * 4 + wave;
  const float* xr = x + (size_t)t * DMODEL;
  float acc[NEXP];
#pragma unroll
  for (int e = 0; e < NEXP; ++e) acc[e] = 0.f;
  for (int i = lane; i < DMODEL; i += 64) {
    float xv = xr[i];
    xb[(size_t)t * DMODEL + i] = (__bf16)xv;
    const float* g = gw + (size_t)i * NEXP;
#pragma unroll
    for (int e = 0; e < NEXP; ++e) acc[e] = fmaf(xv, g[e], acc[e]);
  }
#pragma unroll
  for (int e = 0; e < NEXP; ++e) {
    float v = acc[e];
#pragma unroll
    for (int s = 32; s > 0; s >>= 1) v += __shfl_xor(v, s, 64);
    acc[e] = v;
  }
  if (lane == 0) {
    float mx = -1e30f;
#pragma unroll
    for (int e = 0; e < NEXP; ++e) { acc[e] += gb[e]; mx = fmaxf(mx, acc[e]); }
    float Z = 0.f;
#pragma unroll
    for (int e = 0; e < NEXP; ++e) { acc[e] = expf(acc[e] - mx); Z += acc[e]; }
    int i0 = 0; float s0 = acc[0];
#pragma unroll
    for (int e = 1; e < NEXP; ++e) if (acc[e] > s0) { s0 = acc[e]; i0 = e; }
    int i1 = -1; float s1 = -1e30f;
#pragma unroll
    for (int e = 0; e < NEXP; ++e) if (e != i0 && acc[e] > s1) { s1 = acc[e]; i1 = e; }
    s0 /= Z; s1 /= Z;
    float dn = s0 + s1 + 1e-9f;
    topk_idx[t] = i0 | (i1 << 8);
    topk_w[t] = make_float2(s0 / dn, s1 / dn);
  }
}

// ---------------- per-block expert histogram (LDS atomics only) ----------------
__global__ __launch_bounds__(256) void hist_kernel(
    const int* __restrict__ topk_idx, int* __restrict__ block_hist)
{
  __shared__ int cnt[NEXP];
  int tid = threadIdx.x;
  if (tid < NEXP) cnt[tid] = 0;
  __syncthreads();
  int t = blockIdx.x * TOK_PER_BLK + tid;
  int p = topk_idx[t];
  atomicAdd(&cnt[p & 0xff], 1);
  atomicAdd(&cnt[p >> 8], 1);
  __syncthreads();
  if (tid < NEXP) block_hist[blockIdx.x * NEXP + tid] = cnt[tid];
}

// ---------------- scan: counts, offsets, per-block global bases, aux loss ----------------
__global__ void scan2_kernel(const int* __restrict__ block_hist,
                             int* __restrict__ counts, int* __restrict__ offsets,
                             int* __restrict__ block_base, float* __restrict__ aux_out)
{
  __shared__ int cl[NEXP];
  int lane = threadIdx.x;
  if (lane < NEXP) {
    int s = 0;
    for (int b = 0; b < HIST_BLK; ++b) s += block_hist[b * NEXP + lane];
    cl[lane] = s;
    counts[lane] = s;
  }
  __syncthreads();
  if (lane < NEXP) {
    int off = 0;
    for (int e = 0; e < lane; ++e) off += cl[e];
    offsets[lane] = off;
    int base = off;
    for (int b = 0; b < HIST_BLK; ++b) {
      block_base[b * NEXP + lane] = base;
      base += block_hist[b * NEXP + lane];
    }
  }
  if (lane == 0) {
    int tot = 0; float pen = 0.f;
    const float cap = 1.25f * (float)(T_TOK * 2) / (float)NEXP; // 2560
    for (int e = 0; e < NEXP; ++e) {
      tot += cl[e];
      float ld = (float)cl[e] - cap;
      pen += ld > 0.f ? ld : 0.f;
    }
    offsets[NEXP] = tot;
    aux_out[0] = 0.01f * pen / (float)NEXP / (float)T_TOK;
  }
}

// ---------------- scatter: compact-list positions + inverse map (token -> slots) ----------------
__global__ __launch_bounds__(256) void scatter_kernel(
    const int* __restrict__ topk_idx, const int* __restrict__ block_base,
    int* __restrict__ tok_list, int2* __restrict__ tok_slots)
{
  __shared__ int base[NEXP];
  int tid = threadIdx.x;
  if (tid < NEXP) base[tid] = block_base[blockIdx.x * NEXP + tid];
  __syncthreads();
  int t = blockIdx.x * TOK_PER_BLK + tid;
  int p = topk_idx[t];
  int i0 = p & 0xff, i1 = p >> 8;
  int p0 = atomicAdd(&base[i0], 1);
  tok_list[p0] = t;
  int p1 = atomicAdd(&base[i1], 1);
  tok_list[p1] = t;
  tok_slots[t] = make_int2(p0, p1);
}

// ---------------- tiled transpose fp32[E][R][C] -> bf16[E][C][R] ----------------
template<int R, int C>
__global__ __launch_bounds__(256) void transpose_bf16_kernel(const float* __restrict__ in,
                                                             __bf16* __restrict__ out)
{
  __shared__ float tile[32][33];
  int e = blockIdx.z;
  int c0 = blockIdx.x * 32, r0 = blockIdx.y * 32;
  const float* src = in + ((size_t)e * R + r0) * C + c0;
#pragma unroll
  for (int i = 0; i < 4; ++i) {
    int r = threadIdx.y + i * 8;
    tile[r][threadIdx.x] = src[(size_t)r * C + threadIdx.x];
  }
  __syncthreads();
  __bf16* dst = out + ((size_t)e * C + c0) * R + r0;
#pragma unroll
  for (int i = 0; i < 4; ++i) {
    int c = threadIdx.y + i * 8;
    dst[(size_t)c * R + threadIdx.x] = (__bf16)tile[threadIdx.x][c];
  }
}

// ---------------- grouped GEMM tiles (m97-style: global_load_lds, unpadded LDS) ----------------
#define BM 128
#define BN 64
#define BK 32

// FFN1: h = (x@gp + b) * silu(x@up + b). A gathered via compact tok_list.
__global__ __launch_bounds__(256) void ffn1_kernel(
    const __bf16* __restrict__ xb, const __bf16* __restrict__ gpb, const __bf16* __restrict__ upb,
    const float* __restrict__ gp_b, const float* __restrict__ up_b,
    const int* __restrict__ counts, const int* __restrict__ offsets,
    const int* __restrict__ tok_list, __bf16* __restrict__ h)
{
  int e = blockIdx.z;
  int cnt = counts[e];
  int m0 = blockIdx.y * BM;
  if (m0 >= cnt) return;
  int n0 = blockIdx.x * BN;
  int offe = offsets[e];

  __shared__ __align__(16) __bf16 As[BM * BK];    // 8 KB, unpadded
  __shared__ __align__(16) __bf16 Bgs[BN * BK];   // 4 KB
  __shared__ __align__(16) __bf16 Bus[BN * BK];   // 4 KB
  __shared__ int toks[BM];

  int tid = threadIdx.x;
  if (tid < BM) {
    int r = m0 + tid;
    toks[tid] = tok_list[offe + (r < cnt ? r : cnt - 1)];  // clamp: garbage rows never stored
  }
  __syncthreads();

  int wave = tid >> 6, lane = tid & 63;
  int quad = lane >> 4, l16 = lane & 15;

  // Per-thread staging pointers (advance by BK per iter).
  int rr = tid >> 2, ko = (tid & 3) * 8;
  const __bf16* ga0 = xb + (size_t)toks[rr] * DMODEL + ko;        // A rows 0..63
  const __bf16* ga1 = xb + (size_t)toks[64 + rr] * DMODEL + ko;   // A rows 64..127
  const __bf16* gbg = gpb + ((size_t)e * HID + n0 + rr) * DMODEL + ko;
  const __bf16* gbu = upb + ((size_t)e * HID + n0 + rr) * DMODEL + ko;
  __bf16* la0 = As + tid * 8;
  __bf16* la1 = As + (256 + tid) * 8;
  __bf16* lbg = Bgs + tid * 8;
  __bf16* lbu = Bus + tid * 8;

  f32_4 accg[2][4], accu[2][4];
  {
    f32_4 z = {0.f, 0.f, 0.f, 0.f};
#pragma unroll
    for (int a = 0; a < 2; ++a)
#pragma unroll
      for (int b = 0; b < 4; ++b) { accg[a][b] = z; accu[a][b] = z; }
  }

  for (int k0 = 0; k0 < DMODEL; k0 += BK) {
    gload16(ga0, la0);
    gload16(ga1, la1);
    gload16(gbg, lbg);
    gload16(gbu, lbu);
    ga0 += BK; ga1 += BK; gbg += BK; gbu += BK;
    __syncthreads();  // drains vmcnt -> LDS tiles ready

    bf16_8 af[2];
#pragma unroll
    for (int mb = 0; mb < 2; ++mb)
      af[mb] = *(const bf16_8*)(As + (wave * 32 + mb * 16 + l16) * BK + quad * 8);
#pragma unroll
    for (int nb = 0; nb < 4; ++nb) {
      bf16_8 bg = *(const bf16_8*)(Bgs + (nb * 16 + l16) * BK + quad * 8);
      bf16_8 bu = *(const bf16_8*)(Bus + (nb * 16 + l16) * BK + quad * 8);
#pragma unroll
      for (int mb = 0; mb < 2; ++mb) {
        accg[mb][nb] = __builtin_amdgcn_mfma_f32_16x16x32_bf16(af[mb], bg, accg[mb][nb], 0, 0, 0);
        accu[mb][nb] = __builtin_amdgcn_mfma_f32_16x16x32_bf16(af[mb], bu, accu[mb][nb], 0, 0, 0);
      }
    }
    __syncthreads();  // protect LDS before next staging wave
  }

#pragma unroll
  for (int mb = 0; mb < 2; ++mb)
#pragma unroll
    for (int nb = 0; nb < 4; ++nb)
#pragma unroll
      for (int rg = 0; rg < 4; ++rg) {
        int row = wave * 32 + mb * 16 + quad * 4 + rg;  // C/D: col=lane&15, row=quad*4+reg
        int r = m0 + row;
        if (r < cnt) {
          int n = n0 + nb * 16 + l16;
          float g = accg[mb][nb][rg] + gp_b[e * HID + n];
          float u = accu[mb][nb][rg] + up_b[e * HID + n];
          float sw = u / (1.f + expf(-u));
          h[(size_t)(offe + r) * HID + n] = (__bf16)(g * sw);
        }
      }
}

// FFN2: ybuf[slot] = h[slot] @ dp + b   (coalesced bf16 stores, NO atomics)
__global__ __launch_bounds__(256) void ffn2_kernel(
    const __bf16* __restrict__ h, const __bf16* __restrict__ dpb, const float* __restrict__ dp_b,
    const int* __restrict__ counts, const int* __restrict__ offsets,
    __bf16* __restrict__ ybuf)
{
  int e = blockIdx.z;
  int cnt = counts[e];
  int m0 = blockIdx.y * BM;
  if (m0 >= cnt) return;
  int n0 = blockIdx.x * BN;
  int offe = offsets[e];

  __shared__ __align__(16) __bf16 As[BM * BK];   // 8 KB
  __shared__ __align__(16) __bf16 Bs[BN * BK];   // 4 KB

  int tid = threadIdx.x;
  int wave = tid >> 6, lane = tid & 63;
  int quad = lane >> 4, l16 = lane & 15;

  int rr = tid >> 2, ko = (tid & 3) * 8;
  int ra0 = m0 + rr;        if (ra0 >= cnt) ra0 = cnt - 1;   // clamp: garbage rows never stored
  int ra1 = m0 + 64 + rr;   if (ra1 >= cnt) ra1 = cnt - 1;
  const __bf16* ga0 = h + (size_t)(offe + ra0) * HID + ko;
  const __bf16* ga1 = h + (size_t)(offe + ra1) * HID + ko;
  const __bf16* gb  = dpb + ((size_t)e * DMODEL + n0 + rr) * HID + ko;
  __bf16* la0 = As + tid * 8;
  __bf16* la1 = As + (256 + tid) * 8;
  __bf16* lb  = Bs + tid * 8;

  f32_4 acc[2][4];
  {
    f32_4 z = {0.f, 0.f, 0.f, 0.f};
#pragma unroll
    for (int a = 0; a < 2; ++a)
#pragma unroll
      for (int b = 0; b < 4; ++b) acc[a][b] = z;
  }

  for (int k0 = 0; k0 < HID; k0 += BK) {
    gload16(ga0, la0);
    gload16(ga1, la1);
    gload16(gb, lb);
    ga0 += BK; ga1 += BK; gb += BK;
    __syncthreads();

    bf16_8 af[2];
#pragma unroll
    for (int mb = 0; mb < 2; ++mb)
      af[mb] = *(const bf16_8*)(As + (wave * 32 + mb * 16 + l16) * BK + quad * 8);
#pragma unroll
    for (int nb = 0; nb < 4; ++nb) {
      bf16_8 bb = *(const bf16_8*)(Bs + (nb * 16 + l16) * BK + quad * 8);
#pragma unroll
      for (int mb = 0; mb < 2; ++mb)
        acc[mb][nb] = __builtin_amdgcn_mfma_f32_16x16x32_bf16(af[mb], bb, acc[mb][nb], 0, 0, 0);
    }
    __syncthreads();
  }

#pragma unroll
  for (int mb = 0; mb < 2; ++mb)
#pragma unroll
    for (int nb = 0; nb < 4; ++nb)
#pragma unroll
      for (int rg = 0; rg < 4; ++rg) {
        int row = wave * 32 + mb * 16 + quad * 4 + rg;
        int r = m0 + row;
        if (r < cnt) {
          int n = n0 + nb * 16 + l16;
          float v = acc[mb][nb][rg] + dp_b[e * DMODEL + n];
          ybuf[(size_t)(offe + r) * DMODEL + n] = (__bf16)v;
        }
      }
}

// ---------------- combine: out[t] = w0*y[slot0] + w1*y[slot1] ----------------
__global__ __launch_bounds__(256) void combine_kernel(
    const __bf16* __restrict__ ybuf, const int2* __restrict__ tok_slots,
    const float2* __restrict__ topk_w, float* __restrict__ out)
{
  int tid = threadIdx.x;
  int t = blockIdx.x * 2 + (tid >> 7);
  int d = (tid & 127) * 8;
  int2 sl = tok_slots[t];
  float2 w = topk_w[t];
  bf16_8 y0 = *(const bf16_8*)(ybuf + (size_t)sl.x * DMODEL + d);
  bf16_8 y1 = *(const bf16_8*)(ybuf + (size_t)sl.y * DMODEL + d);
  float* o = out + (size_t)t * DMODEL + d;
  f32_4 r0, r1;
#pragma unroll
  for (int i = 0; i < 4; ++i) r0[i] = w.x * (float)y0[i] + w.y * (float)y1[i];
#pragma unroll
  for (int i = 0; i < 4; ++i) r1[i] = w.x * (float)y0[4 + i] + w.y * (float)y1[4 + i];
  *(f32_4*)o = r0;
  *(f32_4*)(o + 4) = r1;
}

extern "C" void kernel_launch(void* const* d_in, const int* in_sizes, int n_in,
                              void* d_out, int out_size, void* d_ws, size_t ws_size,
                              hipStream_t stream)
{
  const float* x      = (const float*)d_in[0];
  const float* gate_w = (const float*)d_in[1];
  const float* gate_b = (const float*)d_in[2];
  const float* gp_w   = (const float*)d_in[3];
  const float* gp_b   = (const float*)d_in[4];
  const float* up_w   = (const float*)d_in[5];
  const float* up_b   = (const float*)d_in[6];
  const float* dp_w   = (const float*)d_in[7];
  const float* dp_b   = (const float*)d_in[8];

  // Workspace layout — total ~118 MB (below the 119.6 MB watermark proven safe in R1).
  // ybuf (67.1 MB) aliases xb+gpb+upb, which are dead once ffn1 completes.
  char* ws = (char*)d_ws;
  size_t o = 0;
  __bf16* xb  = (__bf16*)(ws + o); o += (size_t)T_TOK * DMODEL * 2;          // 33.55 MB
  __bf16* gpb = (__bf16*)(ws + o); o += (size_t)NEXP * DMODEL * HID * 2;     // 16.78 MB
  __bf16* upb = (__bf16*)(ws + o); o += (size_t)NEXP * DMODEL * HID * 2;     // 16.78 MB
  __bf16* dpb = (__bf16*)(ws + o); o += (size_t)NEXP * HID * DMODEL * 2;     // 16.78 MB
  __bf16* hbuf = (__bf16*)(ws + o); o += (size_t)NASSIGN * HID * 2;          // 33.55 MB
  int*   tok_list = (int*)(ws + o); o += (size_t)NASSIGN * 4;                // 128 KB
  int2*  tok_slots = (int2*)(ws + o); o += (size_t)T_TOK * 8;                // 128 KB
  int*   topk_idx = (int*)(ws + o); o += (size_t)T_TOK * 4;                  // 64 KB
  float2* topk_w  = (float2*)(ws + o); o += (size_t)T_TOK * 8;               // 128 KB
  int*   block_hist = (int*)(ws + o); o += (size_t)HIST_BLK * NEXP * 4;      // 4 KB
  int*   block_base = (int*)(ws + o); o += (size_t)HIST_BLK * NEXP * 4;      // 4 KB
  int*   counts   = (int*)(ws + o); o += 64;
  int*   offsets  = (int*)(ws + o); o += 128;
  __bf16* ybuf = (__bf16*)ws;  // [NASSIGN][DMODEL] bf16 = 67.1 MB, aliases xb/gpb/upb

  float* out = (float*)d_out;
  float* aux = out + (size_t)T_TOK * DMODEL;

  gate_compute_kernel<<<T_TOK / 4, 256, 0, stream>>>(x, gate_w, gate_b, xb, topk_idx, topk_w);
  hist_kernel<<<HIST_BLK, TOK_PER_BLK, 0, stream>>>(topk_idx, block_hist);
  scan2_kernel<<<1, 64, 0, stream>>>(block_hist, counts, offsets, block_base, aux);
  scatter_kernel<<<HIST_BLK, TOK_PER_BLK, 0, stream>>>(topk_idx, block_base, tok_list, tok_slots);
  transpose_bf16_kernel<DMODEL, HID><<<dim3(HID / 32, DMODEL / 32, NEXP), dim3(32, 8), 0, stream>>>(gp_w, gpb);
  transpose_bf16_kernel<DMODEL, HID><<<dim3(HID / 32, DMODEL / 32, NEXP), dim3(32, 8), 0, stream>>>(up_w, upb);
  transpose_bf16_kernel<HID, DMODEL><<<dim3(DMODEL / 32, HID / 32, NEXP), dim3(32, 8), 0, stream>>>(dp_w, dpb);
  ffn1_kernel<<<dim3(HID / BN, T_TOK / BM, NEXP), 256, 0, stream>>>(xb, gpb, upb, gp_b, up_b,
                                                                    counts, offsets, tok_list, hbuf);
  ffn2_kernel<<<dim3(DMODEL / BN, T_TOK / BM, NEXP), 256, 0, stream>>>(hbuf, dpb, dp_b,
                                                                       counts, offsets, ybuf);
  combine_kernel<<<T_TOK / 2, 256, 0, stream>>>(ybuf, tok_slots, topk_w, out);
}